// Round 3
// baseline (92.628 us; speedup 1.0000x reference)
//
#include <hip/hip_runtime.h>

#define H 384
#define W 384
#define C 19
#define NB 4
#define HP 382               // H - K + 1
#define HW (H * W)
#define CHW (C * HW)
#define TOTAL_TERMS 47279376.0f   // NB * 81 * HP*HP

// number of kernel-offsets a in [0,2] with 0 <= a+d <= 2 and 0 <= p-a <= HP-1
__device__ __forceinline__ int multv(int p, int d) {
    int lo = max(max(0, -d), p - (HP - 1));
    int hi = min(min(2, 2 - d), p);
    return max(0, hi - lo + 1);
}

__device__ __forceinline__ float bce_fast(float x, float y) {
    // max(x,0) - x*y + log1p(exp(-|x|)), fast-math variant
    float t = __expf(-fabsf(x));
    return fmaxf(x, 0.0f) - x * y + __logf(1.0f + t);
}

__device__ __forceinline__ float eqlab(const int* __restrict__ lab, int myl,
                                       int qy, int qx) {
    qy = min(qy, H - 1);
    qx = min(max(qx, 0), W - 1);
    return (lab[qy * W + qx] == myl) ? 1.0f : 0.0f;
}

// 4 lanes per 2-pixel group: lane slice s owns channels [5s, min(19,5s+5)).
// Grid: NB*H*(W/2)*4 threads = 1179648 = 4608 blocks x 256.
__global__ __launch_bounds__(256) void affinity_partial(
        const float* __restrict__ logits,
        const int* __restrict__ labels,
        float* __restrict__ partial) {
    const int tid   = blockIdx.x * 256 + threadIdx.x;
    const int slice = tid & 3;
    const int gid   = tid >> 2;            // [0, 294912)
    const int px0   = (gid % 192) * 2;
    const int rs    = gid / 192;
    const int py    = rs % H;
    const int n     = rs / H;

    // clamped staging window: x = x0c .. x0c+5 via 3 aligned float2
    const int x0c = max(0, px0 - 2);
    const int d1  = px0 - x0c;                  // 0 or 2
    const int d2  = min(W - 2, px0 + 2) - x0c;  // 2 or 4 (or ==d1 at right edge)
    const int ro1 = (min(py + 1, H - 1) - py) * W;
    const int ro2 = (min(py + 2, H - 1) - py) * W;

    const float* p0 = logits + (size_t)n * CHW + (size_t)py * W + x0c;

    float acc[26];
#pragma unroll
    for (int o = 0; o < 26; ++o) acc[o] = 0.0f;

    const int cbeg = slice * 5;
    const int cend = min(C, cbeg + 5);
    for (int c = cbeg; c < cend; ++c) {
        const float* pr = p0 + (size_t)c * HW;
        float a[6], b[6], e[6];
        *(float2*)&a[0] = *(const float2*)(pr);
        *(float2*)&a[2] = *(const float2*)(pr + d1);
        *(float2*)&a[4] = *(const float2*)(pr + d2);
        *(float2*)&b[0] = *(const float2*)(pr + ro1);
        *(float2*)&b[2] = *(const float2*)(pr + ro1 + d1);
        *(float2*)&b[4] = *(const float2*)(pr + ro1 + d2);
        *(float2*)&e[0] = *(const float2*)(pr + ro2);
        *(float2*)&e[2] = *(const float2*)(pr + ro2 + d1);
        *(float2*)&e[4] = *(const float2*)(pr + ro2 + d2);

#pragma unroll
        for (int i = 0; i < 2; ++i) {
            const float s = a[2 + i];
            acc[i * 13 + 0] += s * s;             // (0,0)
            acc[i * 13 + 1] += s * a[3 + i];      // (0,1)
            acc[i * 13 + 2] += s * a[4 + i];      // (0,2)
#pragma unroll
            for (int dx = 0; dx < 5; ++dx) {
                acc[i * 13 + 3 + dx] += s * b[i + dx];   // (1, dx-2)
                acc[i * 13 + 8 + dx] += s * e[i + dx];   // (2, dx-2)
            }
        }
    }

    // combine channel slices: 2-round butterfly within the 4-lane group
#pragma unroll
    for (int m = 1; m <= 2; m <<= 1) {
#pragma unroll
        for (int o = 0; o < 26; ++o) acc[o] += __shfl_xor(acc[o], m, 64);
    }

    // epilogue split: slice&1 -> which pixel, slice>>1 -> which offset half
    const int pi = slice & 1;
    const int hf = slice >> 1;
    const int px = px0 + pi;

    float A[13];
#pragma unroll
    for (int k = 0; k < 13; ++k) A[k] = pi ? acc[13 + k] : acc[k];

    const int* lab = labels + (size_t)n * HW;
    const int  myl = lab[py * W + px];

    const int wy0 = multv(py, 0);
    const int wy1 = multv(py, 1);
    const int wy2 = multv(py, 2);
    int wx[5];
#pragma unroll
    for (int dxi = 0; dxi < 5; ++dxi) wx[dxi] = multv(px, dxi - 2);

    float total = 0.0f;
    if (hf == 0) {
        // offsets 0..6: dy=0 (dx=0,1,2) and dy=1 (dx=-2..1)
        total += (float)(wy0 * wx[2]) * bce_fast(A[0], 1.0f);
        total += 2.0f * (float)(wy0 * wx[3]) * bce_fast(A[1], eqlab(lab, myl, py, px + 1));
        total += 2.0f * (float)(wy0 * wx[4]) * bce_fast(A[2], eqlab(lab, myl, py, px + 2));
#pragma unroll
        for (int dxi = 0; dxi < 4; ++dxi)
            total += 2.0f * (float)(wy1 * wx[dxi]) *
                     bce_fast(A[3 + dxi], eqlab(lab, myl, py + 1, px + dxi - 2));
    } else {
        // offsets 7..12: dy=1 (dx=2) and dy=2 (dx=-2..2)
        total += 2.0f * (float)(wy1 * wx[4]) * bce_fast(A[7], eqlab(lab, myl, py + 1, px + 2));
#pragma unroll
        for (int dxi = 0; dxi < 5; ++dxi)
            total += 2.0f * (float)(wy2 * wx[dxi]) *
                     bce_fast(A[8 + dxi], eqlab(lab, myl, py + 2, px + dxi - 2));
    }

    // wave reduce + cross-wave via LDS
#pragma unroll
    for (int off = 32; off > 0; off >>= 1) total += __shfl_down(total, off, 64);
    __shared__ float sm[4];
    const int lane = threadIdx.x & 63, wid = threadIdx.x >> 6;
    if (lane == 0) sm[wid] = total;
    __syncthreads();
    if (threadIdx.x == 0)
        partial[blockIdx.x] = sm[0] + sm[1] + sm[2] + sm[3];
}

__global__ __launch_bounds__(256) void reduce_final(
        const float* __restrict__ partial, int n, float* __restrict__ out) {
    float s = 0.0f;
    for (int i = threadIdx.x; i < n; i += 256) s += partial[i];
#pragma unroll
    for (int off = 32; off > 0; off >>= 1) s += __shfl_down(s, off, 64);
    __shared__ float sm[4];
    const int lane = threadIdx.x & 63, wid = threadIdx.x >> 6;
    if (lane == 0) sm[wid] = s;
    __syncthreads();
    if (threadIdx.x == 0)
        out[0] = (sm[0] + sm[1] + sm[2] + sm[3]) / TOTAL_TERMS;
}

extern "C" void kernel_launch(void* const* d_in, const int* in_sizes, int n_in,
                              void* d_out, int out_size, void* d_ws, size_t ws_size,
                              hipStream_t stream) {
    const float* logits = (const float*)d_in[0];
    const int*   labels = (const int*)d_in[1];
    float* out     = (float*)d_out;
    float* partial = (float*)d_ws;   // 4608 floats

    const int nthreads = NB * H * (W / 2) * 4;   // 1179648
    const int nblocks  = nthreads / 256;         // 4608

    affinity_partial<<<nblocks, 256, 0, stream>>>(logits, labels, partial);
    reduce_final<<<1, 256, 0, stream>>>(partial, nblocks, out);
}

// Round 4
// 33.606 us; speedup vs baseline: 2.7563x; 2.7563x over previous
//
#include <hip/hip_runtime.h>

#define H 384
#define W 384
#define C 19
#define NB 4
#define HP 382               // H - K + 1
#define HW (H * W)
#define CHW (C * HW)
#define TOTAL_TERMS 47279376.0f   // NB * 81 * HP*HP

// number of kernel-offsets a in [0,2] with 0 <= a+d <= 2 and 0 <= p-a <= HP-1
__device__ __forceinline__ int multv(int p, int d) {
    int lo = max(max(0, -d), p - (HP - 1));
    int hi = min(min(2, 2 - d), p);
    return max(0, hi - lo + 1);
}

__device__ __forceinline__ float bce_fast(float x, float y) {
    // max(x,0) - x*y + log1p(exp(-|x|)), fast-math variant
    float t = __expf(-fabsf(x));
    return fmaxf(x, 0.0f) - x * y + __logf(1.0f + t);
}

// Each thread owns 4 consecutive x-pixels, but only HALF the 13 offsets:
//   parity 0 (waves 0,2): (0,0) (0,1) (0,2) (1,-2..1)   [7 offsets]
//   parity 1 (waves 1,3): (1,2) (2,-2..2)               [6 offsets]
// Parity is per-WAVE (wid&1) -> no divergence. No cross-lane combine needed.
// Grid: NB*H*96 groups = 147456; 128 groups/block -> 1152 blocks x 256.
__global__ __launch_bounds__(256) void affinity_partial(
        const float* __restrict__ logits,
        const int* __restrict__ labels,
        float* __restrict__ partial) {
    const int wid  = threadIdx.x >> 6;
    const int lane = threadIdx.x & 63;
    const int par  = wid & 1;
    const int g    = blockIdx.x * 128 + (wid >> 1) * 64 + lane;  // pixel group
    const int px0  = (g % 96) * 4;
    const int rs   = g / 96;
    const int py   = rs % H;
    const int n    = rs / H;

    // staging window cols x0c..x0c+11 via aligned float4 at +0, +d1, +d2.
    // invariant (weight>0 terms): arr[j] == column px0 + j - 4.
    const int x0c = max(0, px0 - 4);
    const int d1  = px0 - x0c;                 // 0 or 4
    const int d2  = min(W - 4, px0 + 4) - x0c; // 4 or 8
    const int ro1 = (min(py + 1, H - 1) - py) * W;
    const int ro2 = (min(py + 2, H - 1) - py) * W;

    const float* p0  = logits + (size_t)n * CHW + (size_t)py * W + x0c;
    const int*   lb0 = labels + (size_t)n * HW + (size_t)py * W + x0c;

    const int wy0 = multv(py, 0);
    const int wy1 = multv(py, 1);
    const int wy2 = multv(py, 2);

    float total = 0.0f;

    if (par == 0) {
        float acc[28];
#pragma unroll
        for (int o = 0; o < 28; ++o) acc[o] = 0.0f;

        for (int c = 0; c < C; ++c) {
            const float* pr = p0 + (size_t)c * HW;
            float a[12], b[12];
            *(float4*)&a[0] = *(const float4*)(pr);
            *(float4*)&a[4] = *(const float4*)(pr + d1);
            *(float4*)&a[8] = *(const float4*)(pr + d2);
            *(float4*)&b[0] = *(const float4*)(pr + ro1);
            *(float4*)&b[4] = *(const float4*)(pr + ro1 + d1);
            *(float4*)&b[8] = *(const float4*)(pr + ro1 + d2);
#pragma unroll
            for (int i = 0; i < 4; ++i) {
                const float s = a[4 + i];
                acc[i * 7 + 0] += s * s;            // (0,0)
                acc[i * 7 + 1] += s * a[5 + i];     // (0,1)
                acc[i * 7 + 2] += s * a[6 + i];     // (0,2)
#pragma unroll
                for (int dxi = 0; dxi < 4; ++dxi)   // (1, dxi-2), dxi 0..3
                    acc[i * 7 + 3 + dxi] += s * b[2 + i + dxi];
            }
        }

        int la[12], lbr[12];
        *(int4*)&la[0]  = *(const int4*)(lb0);
        *(int4*)&la[4]  = *(const int4*)(lb0 + d1);
        *(int4*)&la[8]  = *(const int4*)(lb0 + d2);
        *(int4*)&lbr[0] = *(const int4*)(lb0 + ro1);
        *(int4*)&lbr[4] = *(const int4*)(lb0 + ro1 + d1);
        *(int4*)&lbr[8] = *(const int4*)(lb0 + ro1 + d2);

#pragma unroll
        for (int i = 0; i < 4; ++i) {
            const int px = px0 + i;
            int wx[5];
#pragma unroll
            for (int dxi = 0; dxi < 5; ++dxi) wx[dxi] = multv(px, dxi - 2);
            const int ls = la[4 + i];
            total += (float)(wy0 * wx[2]) * bce_fast(acc[i * 7 + 0], 1.0f);
            total += 2.0f * (float)(wy0 * wx[3]) *
                     bce_fast(acc[i * 7 + 1], (ls == la[5 + i]) ? 1.0f : 0.0f);
            total += 2.0f * (float)(wy0 * wx[4]) *
                     bce_fast(acc[i * 7 + 2], (ls == la[6 + i]) ? 1.0f : 0.0f);
#pragma unroll
            for (int dxi = 0; dxi < 4; ++dxi)
                total += 2.0f * (float)(wy1 * wx[dxi]) *
                         bce_fast(acc[i * 7 + 3 + dxi],
                                  (ls == lbr[2 + i + dxi]) ? 1.0f : 0.0f);
        }
    } else {
        float acc[24];
#pragma unroll
        for (int o = 0; o < 24; ++o) acc[o] = 0.0f;

        for (int c = 0; c < C; ++c) {
            const float* pr = p0 + (size_t)c * HW;
            float sa[4], b[12], e[12];
            *(float4*)&sa[0] = *(const float4*)(pr + d1);        // s = cols px0..px0+3
            *(float4*)&b[4]  = *(const float4*)(pr + ro1 + d1);
            *(float4*)&b[8]  = *(const float4*)(pr + ro1 + d2);
            *(float4*)&e[0]  = *(const float4*)(pr + ro2);
            *(float4*)&e[4]  = *(const float4*)(pr + ro2 + d1);
            *(float4*)&e[8]  = *(const float4*)(pr + ro2 + d2);
#pragma unroll
            for (int i = 0; i < 4; ++i) {
                const float s = sa[i];
                acc[i * 6 + 0] += s * b[6 + i];     // (1, 2)
#pragma unroll
                for (int dxi = 0; dxi < 5; ++dxi)   // (2, dxi-2)
                    acc[i * 6 + 1 + dxi] += s * e[2 + i + dxi];
            }
        }

        int la[4], lbr[12], ler[12];
        *(int4*)&la[0]  = *(const int4*)(lb0 + d1);
        *(int4*)&lbr[4] = *(const int4*)(lb0 + ro1 + d1);
        *(int4*)&lbr[8] = *(const int4*)(lb0 + ro1 + d2);
        *(int4*)&ler[0] = *(const int4*)(lb0 + ro2);
        *(int4*)&ler[4] = *(const int4*)(lb0 + ro2 + d1);
        *(int4*)&ler[8] = *(const int4*)(lb0 + ro2 + d2);

#pragma unroll
        for (int i = 0; i < 4; ++i) {
            const int px = px0 + i;
            int wx[5];
#pragma unroll
            for (int dxi = 0; dxi < 5; ++dxi) wx[dxi] = multv(px, dxi - 2);
            const int ls = la[i];
            total += 2.0f * (float)(wy1 * wx[4]) *
                     bce_fast(acc[i * 6 + 0], (ls == lbr[6 + i]) ? 1.0f : 0.0f);
#pragma unroll
            for (int dxi = 0; dxi < 5; ++dxi)
                total += 2.0f * (float)(wy2 * wx[dxi]) *
                         bce_fast(acc[i * 6 + 1 + dxi],
                                  (ls == ler[2 + i + dxi]) ? 1.0f : 0.0f);
        }
    }

    // block reduction: wave shuffle then LDS across the 4 waves
#pragma unroll
    for (int off = 32; off > 0; off >>= 1) total += __shfl_down(total, off, 64);
    __shared__ float sm[4];
    if (lane == 0) sm[wid] = total;
    __syncthreads();
    if (threadIdx.x == 0)
        partial[blockIdx.x] = sm[0] + sm[1] + sm[2] + sm[3];
}

__global__ __launch_bounds__(256) void reduce_final(
        const float* __restrict__ partial, int n, float* __restrict__ out) {
    float s = 0.0f;
    for (int i = threadIdx.x; i < n; i += 256) s += partial[i];
#pragma unroll
    for (int off = 32; off > 0; off >>= 1) s += __shfl_down(s, off, 64);
    __shared__ float sm[4];
    const int lane = threadIdx.x & 63, wid = threadIdx.x >> 6;
    if (lane == 0) sm[wid] = s;
    __syncthreads();
    if (threadIdx.x == 0)
        out[0] = (sm[0] + sm[1] + sm[2] + sm[3]) / TOTAL_TERMS;
}

extern "C" void kernel_launch(void* const* d_in, const int* in_sizes, int n_in,
                              void* d_out, int out_size, void* d_ws, size_t ws_size,
                              hipStream_t stream) {
    const float* logits = (const float*)d_in[0];
    const int*   labels = (const int*)d_in[1];
    float* out     = (float*)d_out;
    float* partial = (float*)d_ws;   // 1152 floats

    const int ngroups = NB * H * 96;          // 147456 pixel groups
    const int nblocks = ngroups / 128;        // 1152 (2 groups-of-64 x 2 parities)

    affinity_partial<<<nblocks, 256, 0, stream>>>(logits, labels, partial);
    reduce_final<<<1, 256, 0, stream>>>(partial, nblocks, out);
}